// Round 1
// baseline (1970.327 us; speedup 1.0000x reference)
//
#include <hip/hip_runtime.h>

// Problem constants (fixed by the reference setup):
//   N  = 117000 vocab rows, BT = B*T = 4*64 = 256, E = 500000 edges (from in_sizes[1])
#define NN 117000
#define BT 256

// --- row_sum[i] = sum of vv[e] over edges with row[e]==i -------------------
__global__ void rowsum_kernel(const int* __restrict__ row, const float* __restrict__ vv,
                              float* __restrict__ row_sum, int E) {
    int e = blockIdx.x * blockDim.x + threadIdx.x;
    if (e < E) atomicAdd(&row_sum[row[e]], vv[e]);
}

// --- xT[i*BT + bt] = logits[bt*NN + i]  (tiled LDS transpose) --------------
__global__ void transpose_kernel(const float* __restrict__ logits, float* __restrict__ xT) {
    __shared__ float s[32][33];
    int tx = threadIdx.x & 31;       // fast dim
    int ty = threadIdx.x >> 5;       // 0..7
    int i0  = blockIdx.x * 32;
    int bt0 = blockIdx.y * 32;
    int i = i0 + tx;
#pragma unroll
    for (int r = 0; r < 4; ++r) {
        int bt = bt0 + ty + r * 8;
        if (i < NN) s[ty + r * 8][tx] = logits[(size_t)bt * NN + i];   // coalesced over i
    }
    __syncthreads();
#pragma unroll
    for (int r = 0; r < 4; ++r) {
        int i2 = i0 + ty + r * 8;
        if (i2 < NN) xT[(size_t)i2 * BT + bt0 + tx] = s[tx][ty + r * 8]; // coalesced over bt
    }
}

// --- acc[row, :] += vv[e] * xT[col, :]   (one 64-lane wave per edge) -------
__global__ void edge_kernel(const int* __restrict__ row, const int* __restrict__ col,
                            const float* __restrict__ vv, const float* __restrict__ xT,
                            float* __restrict__ acc, int E) {
    int e = blockIdx.x * 4 + (threadIdx.x >> 6);
    if (e >= E) return;
    int lane = threadIdx.x & 63;
    int r = row[e];
    int c = col[e];
    float v = vv[e];
    const float4* src = (const float4*)(xT + (size_t)c * BT);
    float4 x4 = src[lane];                       // contiguous 1 KB per edge
    float* dst = acc + (size_t)r * BT + lane * 4;
    atomicAdd(dst + 0, v * x4.x);
    atomicAdd(dst + 1, v * x4.y);
    atomicAdd(dst + 2, v * x4.z);
    atomicAdd(dst + 3, v * x4.w);
}

// --- tier-2 fallback: gather straight from logits (strided, LLC-cached) ----
__global__ void edge_kernel_direct(const int* __restrict__ row, const int* __restrict__ col,
                                   const float* __restrict__ vv, const float* __restrict__ logits,
                                   float* __restrict__ acc, int E) {
    int e = blockIdx.x * 4 + (threadIdx.x >> 6);
    if (e >= E) return;
    int lane = threadIdx.x & 63;
    int r = row[e];
    int c = col[e];
    float v = vv[e];
    float* dst = acc + (size_t)r * BT + lane * 4;
#pragma unroll
    for (int k = 0; k < 4; ++k) {
        int bt = lane * 4 + k;
        float x = logits[(size_t)bt * NN + c];
        atomicAdd(dst + k, v * x);
    }
}

// --- out[bt,i] = logits[bt,i] + acc[i,bt] / row_sum[i]  (tiled transpose) --
__global__ void finalize_kernel(const float* __restrict__ logits, const float* __restrict__ acc,
                                const float* __restrict__ row_sum, float* __restrict__ out) {
    __shared__ float s[32][33];
    __shared__ float rs[32];
    int tx = threadIdx.x & 31;
    int ty = threadIdx.x >> 5;
    int i0  = blockIdx.x * 32;
    int bt0 = blockIdx.y * 32;
#pragma unroll
    for (int r = 0; r < 4; ++r) {
        int il = ty + r * 8;
        int i = i0 + il;
        if (i < NN) s[il][tx] = acc[(size_t)i * BT + bt0 + tx];   // coalesced over bt
    }
    if (threadIdx.x < 32) {
        int i = i0 + (int)threadIdx.x;
        rs[threadIdx.x] = (i < NN) ? row_sum[i] : 1.0f;
    }
    __syncthreads();
#pragma unroll
    for (int r = 0; r < 4; ++r) {
        int bt = bt0 + ty + r * 8;
        int i = i0 + tx;
        if (i < NN) {
            size_t idx = (size_t)bt * NN + i;
            out[idx] = logits[idx] + s[tx][ty + r * 8] / rs[tx];  // coalesced over i
        }
    }
}

// --- tier-3 fallback: scatter pre-normalized contribs straight into out ----
__global__ void edge_kernel_out(const int* __restrict__ row, const int* __restrict__ col,
                                const float* __restrict__ vv, const float* __restrict__ row_sum,
                                const float* __restrict__ logits, float* __restrict__ out, int E) {
    int e = blockIdx.x * 4 + (threadIdx.x >> 6);
    if (e >= E) return;
    int lane = threadIdx.x & 63;
    int r = row[e];
    int c = col[e];
    float scale = vv[e] / row_sum[r];
#pragma unroll
    for (int k = 0; k < 4; ++k) {
        int bt = lane * 4 + k;
        atomicAdd(&out[(size_t)bt * NN + r], scale * logits[(size_t)bt * NN + c]);
    }
}

__global__ void add_logits_kernel(const float* __restrict__ logits, float* __restrict__ out, size_t n) {
    size_t i = (size_t)blockIdx.x * blockDim.x + threadIdx.x;
    if (i < n) out[i] += logits[i];
}

extern "C" void kernel_launch(void* const* d_in, const int* in_sizes, int n_in,
                              void* d_out, int out_size, void* d_ws, size_t ws_size,
                              hipStream_t stream) {
    const float* logits = (const float*)d_in[0];
    const float* vv     = (const float*)d_in[1];
    const int*   ei     = (const int*)d_in[2];
    const int E = in_sizes[1];
    const int* row = ei;        // edge_index[0] = first E ints
    const int* col = ei + E;    // edge_index[1] = next E ints
    float* out = (float*)d_out;

    const size_t accN  = (size_t)NN * BT;                 // 29,952,000 elems
    const size_t need1 = (2 * accN + NN) * sizeof(float); // xT + acc + row_sum
    const size_t need2 = (accN + NN) * sizeof(float);     // acc + row_sum

    dim3 tgrid((NN + 31) / 32, BT / 32);
    const int rs_blocks   = (E + 255) / 256;
    const int edge_blocks = (E + 3) / 4;

    if (ws_size >= need1) {
        // Tier 1: transpose gather source for fully-coalesced edge kernel.
        float* acc     = (float*)d_ws;
        float* xT      = acc + accN;
        float* row_sum = xT + accN;
        hipMemsetAsync(acc, 0, accN * sizeof(float), stream);
        hipMemsetAsync(row_sum, 0, NN * sizeof(float), stream);
        rowsum_kernel<<<rs_blocks, 256, 0, stream>>>(row, vv, row_sum, E);
        transpose_kernel<<<tgrid, 256, 0, stream>>>(logits, xT);
        edge_kernel<<<edge_blocks, 256, 0, stream>>>(row, col, vv, xT, acc, E);
        finalize_kernel<<<tgrid, 256, 0, stream>>>(logits, acc, row_sum, out);
    } else if (ws_size >= need2) {
        // Tier 2: no room for xT — strided gather from logits (LLC-resident).
        float* acc     = (float*)d_ws;
        float* row_sum = acc + accN;
        hipMemsetAsync(acc, 0, accN * sizeof(float), stream);
        hipMemsetAsync(row_sum, 0, NN * sizeof(float), stream);
        rowsum_kernel<<<rs_blocks, 256, 0, stream>>>(row, vv, row_sum, E);
        edge_kernel_direct<<<edge_blocks, 256, 0, stream>>>(row, col, vv, logits, acc, E);
        finalize_kernel<<<tgrid, 256, 0, stream>>>(logits, acc, row_sum, out);
    } else {
        // Tier 3: minimal workspace — scatter normalized contribs into out.
        float* row_sum = (float*)d_ws;
        hipMemsetAsync(row_sum, 0, NN * sizeof(float), stream);
        hipMemsetAsync(out, 0, accN * sizeof(float), stream);
        rowsum_kernel<<<rs_blocks, 256, 0, stream>>>(row, vv, row_sum, E);
        edge_kernel_out<<<edge_blocks, 256, 0, stream>>>(row, col, vv, row_sum, logits, out, E);
        add_logits_kernel<<<(unsigned)((accN + 255) / 256), 256, 0, stream>>>(logits, out, accN);
    }
}

// Round 2
// 769.299 us; speedup vs baseline: 2.5612x; 2.5612x over previous
//
#include <hip/hip_runtime.h>

// Problem constants (fixed by the reference setup):
//   N = 117000 vocab rows, BT = B*T = 4*64 = 256, E = 500000 edges (in_sizes[1])
#define NN 117000
#define BT 256
#define SCAN_T 1024

// ===================== CSR build =====================

// count[r] += 1 for each edge
__global__ void hist_kernel(const int* __restrict__ row, int* __restrict__ count, int E) {
    int e = blockIdx.x * blockDim.x + threadIdx.x;
    if (e < E) atomicAdd(&count[row[e]], 1);
}

// In-place exclusive scan of count[0..NN) -> row_ptr (same array), plus cursor copy.
// Single block of 1024 threads, ~115 elements/thread.
__global__ void scan_kernel(int* __restrict__ row_ptr, int* __restrict__ cursor) {
    __shared__ int s[SCAN_T];
    int t = threadIdx.x;
    const int chunk = (NN + SCAN_T - 1) / SCAN_T;   // 115
    int base = t * chunk;
    int sum = 0;
    for (int j = 0; j < chunk; ++j) {
        int idx = base + j;
        if (idx < NN) sum += row_ptr[idx];
    }
    s[t] = sum;
    __syncthreads();
    // Hillis-Steele inclusive scan over the 1024 partials
    for (int off = 1; off < SCAN_T; off <<= 1) {
        int v = (t >= off) ? s[t - off] : 0;
        __syncthreads();
        s[t] += v;
        __syncthreads();
    }
    int running = (t == 0) ? 0 : s[t - 1];          // exclusive prefix of this chunk
    for (int j = 0; j < chunk; ++j) {
        int idx = base + j;
        if (idx < NN) {
            int c = row_ptr[idx];                    // read count before overwrite
            row_ptr[idx] = running;
            cursor[idx]  = running;
            running += c;
        }
    }
    if (t == SCAN_T - 1) row_ptr[NN] = running;      // == E
}

// Scatter edges into row-sorted order (col_s, vv_s). Order within a row is
// nondeterministic — only changes fp32 summation order, well within tolerance.
__global__ void scatter_kernel(const int* __restrict__ row, const int* __restrict__ col,
                               const float* __restrict__ vv, int* __restrict__ cursor,
                               int* __restrict__ col_s, float* __restrict__ vv_s, int E) {
    int e = blockIdx.x * blockDim.x + threadIdx.x;
    if (e >= E) return;
    int p = atomicAdd(&cursor[row[e]], 1);
    col_s[p] = col[e];
    vv_s[p]  = vv[e];
}

// ===================== main pipeline =====================

// xT[i*BT + bt] = logits[bt*NN + i]  (tiled LDS transpose)
__global__ void transpose_kernel(const float* __restrict__ logits, float* __restrict__ xT) {
    __shared__ float s[32][33];
    int tx = threadIdx.x & 31;
    int ty = threadIdx.x >> 5;
    int i0  = blockIdx.x * 32;
    int bt0 = blockIdx.y * 32;
    int i = i0 + tx;
#pragma unroll
    for (int r = 0; r < 4; ++r) {
        int bt = bt0 + ty + r * 8;
        if (i < NN) s[ty + r * 8][tx] = logits[(size_t)bt * NN + i];   // coalesced over i
    }
    __syncthreads();
#pragma unroll
    for (int r = 0; r < 4; ++r) {
        int i2 = i0 + ty + r * 8;
        if (i2 < NN) xT[(size_t)i2 * BT + bt0 + tx] = s[tx][ty + r * 8]; // coalesced over bt
    }
}

// One 64-lane wave per row: accT[i,:] = (sum_e vv*xT[col_e,:]) / (sum_e vv).
// No atomics; one contiguous 1 KB gather per edge, one 1 KB write per row.
__global__ void row_gather_kernel(const int* __restrict__ row_ptr,
                                  const int* __restrict__ col_s,
                                  const float* __restrict__ vv_s,
                                  const float* __restrict__ xT,
                                  float* __restrict__ accT) {
    int i = blockIdx.x * 4 + (threadIdx.x >> 6);
    if (i >= NN) return;
    int lane = threadIdx.x & 63;
    int k0 = row_ptr[i], k1 = row_ptr[i + 1];
    float4 acc = make_float4(0.f, 0.f, 0.f, 0.f);
    float rs = 0.f;
    for (int k = k0; k < k1; ++k) {
        int   c = col_s[k];      // wave-uniform broadcast load
        float v = vv_s[k];
        rs += v;
        float4 x = ((const float4*)(xT + (size_t)c * BT))[lane];
        acc.x += v * x.x; acc.y += v * x.y; acc.z += v * x.z; acc.w += v * x.w;
    }
    float inv = (rs > 0.f) ? (1.0f / rs) : 0.f;
    ((float4*)(accT + (size_t)i * BT))[lane] =
        make_float4(acc.x * inv, acc.y * inv, acc.z * inv, acc.w * inv);
}

// out[bt,i] = logits[bt,i] + accT[i,bt]  (tiled transpose; accT pre-normalized)
__global__ void finalize_kernel(const float* __restrict__ logits, const float* __restrict__ accT,
                                float* __restrict__ out) {
    __shared__ float s[32][33];
    int tx = threadIdx.x & 31;
    int ty = threadIdx.x >> 5;
    int i0  = blockIdx.x * 32;
    int bt0 = blockIdx.y * 32;
#pragma unroll
    for (int r = 0; r < 4; ++r) {
        int il = ty + r * 8;
        int i = i0 + il;
        if (i < NN) s[il][tx] = accT[(size_t)i * BT + bt0 + tx];   // coalesced over bt
    }
    __syncthreads();
#pragma unroll
    for (int r = 0; r < 4; ++r) {
        int bt = bt0 + ty + r * 8;
        int i = i0 + tx;
        if (i < NN) {
            size_t idx = (size_t)bt * NN + i;
            out[idx] = logits[idx] + s[tx][ty + r * 8];            // coalesced over i
        }
    }
}

// ===================== fallback (atomic) path kernels =====================

__global__ void rowsum_kernel(const int* __restrict__ row, const float* __restrict__ vv,
                              float* __restrict__ row_sum, int E) {
    int e = blockIdx.x * blockDim.x + threadIdx.x;
    if (e < E) atomicAdd(&row_sum[row[e]], vv[e]);
}

__global__ void edge_kernel(const int* __restrict__ row, const int* __restrict__ col,
                            const float* __restrict__ vv, const float* __restrict__ xT,
                            float* __restrict__ acc, int E) {
    int e = blockIdx.x * 4 + (threadIdx.x >> 6);
    if (e >= E) return;
    int lane = threadIdx.x & 63;
    int r = row[e];
    int c = col[e];
    float v = vv[e];
    float4 x4 = ((const float4*)(xT + (size_t)c * BT))[lane];
    float* dst = acc + (size_t)r * BT + lane * 4;
    atomicAdd(dst + 0, v * x4.x);
    atomicAdd(dst + 1, v * x4.y);
    atomicAdd(dst + 2, v * x4.z);
    atomicAdd(dst + 3, v * x4.w);
}

__global__ void finalize_div_kernel(const float* __restrict__ logits, const float* __restrict__ acc,
                                    const float* __restrict__ row_sum, float* __restrict__ out) {
    __shared__ float s[32][33];
    __shared__ float rs[32];
    int tx = threadIdx.x & 31;
    int ty = threadIdx.x >> 5;
    int i0  = blockIdx.x * 32;
    int bt0 = blockIdx.y * 32;
#pragma unroll
    for (int r = 0; r < 4; ++r) {
        int il = ty + r * 8;
        int i = i0 + il;
        if (i < NN) s[il][tx] = acc[(size_t)i * BT + bt0 + tx];
    }
    if (threadIdx.x < 32) {
        int i = i0 + (int)threadIdx.x;
        rs[threadIdx.x] = (i < NN) ? row_sum[i] : 1.0f;
    }
    __syncthreads();
#pragma unroll
    for (int r = 0; r < 4; ++r) {
        int bt = bt0 + ty + r * 8;
        int i = i0 + tx;
        if (i < NN) {
            size_t idx = (size_t)bt * NN + i;
            out[idx] = logits[idx] + s[tx][ty + r * 8] / rs[tx];
        }
    }
}

extern "C" void kernel_launch(void* const* d_in, const int* in_sizes, int n_in,
                              void* d_out, int out_size, void* d_ws, size_t ws_size,
                              hipStream_t stream) {
    const float* logits = (const float*)d_in[0];
    const float* vv     = (const float*)d_in[1];
    const int*   ei     = (const int*)d_in[2];
    const int E = in_sizes[1];
    const int* row = ei;        // edge_index[0]
    const int* col = ei + E;    // edge_index[1]
    float* out = (float*)d_out;

    const size_t accN = (size_t)NN * BT;   // 29,952,000 elems

    dim3 tgrid((NN + 31) / 32, BT / 32);
    const int e_blocks   = (E + 255) / 256;
    const int row_blocks = (NN + 3) / 4;

    // CSR-path workspace layout
    //   xT      : accN floats
    //   accT    : accN floats
    //   row_ptr : NN+1 ints (doubles as count during histogram)
    //   cursor  : NN ints
    //   col_s   : E ints
    //   vv_s    : E floats
    const size_t need_csr = (2 * accN) * sizeof(float)
                          + (size_t)(NN + 1 + NN + E) * sizeof(int)
                          + (size_t)E * sizeof(float);
    const size_t need_atomic = (2 * accN + NN) * sizeof(float);

    if (ws_size >= need_csr) {
        float* xT      = (float*)d_ws;
        float* accT    = xT + accN;
        int*   row_ptr = (int*)(accT + accN);
        int*   cursor  = row_ptr + (NN + 1);
        int*   col_s   = cursor + NN;
        float* vv_s    = (float*)(col_s + E);

        hipMemsetAsync(row_ptr, 0, (NN + 1) * sizeof(int), stream);
        hist_kernel<<<e_blocks, 256, 0, stream>>>(row, row_ptr, E);
        scan_kernel<<<1, SCAN_T, 0, stream>>>(row_ptr, cursor);
        scatter_kernel<<<e_blocks, 256, 0, stream>>>(row, col, vv, cursor, col_s, vv_s, E);
        transpose_kernel<<<tgrid, 256, 0, stream>>>(logits, xT);
        row_gather_kernel<<<row_blocks, 256, 0, stream>>>(row_ptr, col_s, vv_s, xT, accT);
        finalize_kernel<<<tgrid, 256, 0, stream>>>(logits, accT, out);
    } else {
        // Fallback: previous atomic-scatter path (known-passing).
        float* acc     = (float*)d_ws;
        float* xT      = acc + accN;
        float* row_sum = xT + accN;
        (void)need_atomic;
        hipMemsetAsync(acc, 0, accN * sizeof(float), stream);
        hipMemsetAsync(row_sum, 0, NN * sizeof(float), stream);
        rowsum_kernel<<<e_blocks, 256, 0, stream>>>(row, vv, row_sum, E);
        transpose_kernel<<<tgrid, 256, 0, stream>>>(logits, xT);
        edge_kernel<<<(E + 3) / 4, 256, 0, stream>>>(row, col, vv, xT, acc, E);
        finalize_div_kernel<<<tgrid, 256, 0, stream>>>(logits, acc, row_sum, out);
    }
}

// Round 3
// 471.453 us; speedup vs baseline: 4.1793x; 1.6318x over previous
//
#include <hip/hip_runtime.h>

// Problem constants (fixed by the reference setup):
//   N = 117000 vocab rows, BT = B*T = 4*64 = 256, E = 500000 edges (in_sizes[1])
#define NN 117000
#define BT 256

// Scan decomposition: 115 blocks x 256 threads x 4 elems = 117760 slots >= NN
#define SCAN_CHUNK 1024
#define SCAN_NB ((NN + SCAN_CHUNK - 1) / SCAN_CHUNK)   // 115
#define SCAN_P2_T 128                                   // >= SCAN_NB

// ===================== CSR build =====================

// count[r] += 1 for each edge
__global__ void hist_kernel(const int* __restrict__ row, int* __restrict__ count, int E) {
    int e = blockIdx.x * blockDim.x + threadIdx.x;
    if (e < E) atomicAdd(&count[row[e]], 1);
}

// Phase 1: per-block sum of each 1024-count chunk.
__global__ void scan_phase1(const int* __restrict__ count, int* __restrict__ block_sums) {
    __shared__ int s[256];
    int base = blockIdx.x * SCAN_CHUNK + threadIdx.x * 4;
    int sum = 0;
#pragma unroll
    for (int j = 0; j < 4; ++j) {
        int idx = base + j;
        if (idx < NN) sum += count[idx];
    }
    s[threadIdx.x] = sum;
    __syncthreads();
    for (int off = 128; off > 0; off >>= 1) {
        if (threadIdx.x < off) s[threadIdx.x] += s[threadIdx.x + off];
        __syncthreads();
    }
    if (threadIdx.x == 0) block_sums[blockIdx.x] = s[0];
}

// Phase 2: single small block — exclusive scan of the 115 block sums,
// and write row_ptr[NN] = E.
__global__ void scan_phase2(int* __restrict__ block_sums, int* __restrict__ row_ptr) {
    __shared__ int s[SCAN_P2_T];
    int t = threadIdx.x;
    int v = (t < SCAN_NB) ? block_sums[t] : 0;
    s[t] = v;
    __syncthreads();
    for (int off = 1; off < SCAN_P2_T; off <<= 1) {
        int u = (t >= off) ? s[t - off] : 0;
        __syncthreads();
        s[t] += u;
        __syncthreads();
    }
    if (t < SCAN_NB) block_sums[t] = (t == 0) ? 0 : s[t - 1];  // exclusive offsets
    if (t == SCAN_P2_T - 1) row_ptr[NN] = s[SCAN_NB - 1];      // total == E
}

// Phase 3: in-place exclusive scan of counts within each chunk + block offset.
// Safe in place: each thread reads its 4 counts into regs before overwriting.
__global__ void scan_phase3(int* __restrict__ row_ptr, const int* __restrict__ block_offs,
                            int* __restrict__ cursor) {
    __shared__ int s[256];
    int base = blockIdx.x * SCAN_CHUNK + threadIdx.x * 4;
    int v[4];
    int sum = 0;
#pragma unroll
    for (int j = 0; j < 4; ++j) {
        int idx = base + j;
        v[j] = (idx < NN) ? row_ptr[idx] : 0;
        sum += v[j];
    }
    s[threadIdx.x] = sum;
    __syncthreads();
    for (int off = 1; off < 256; off <<= 1) {
        int u = (threadIdx.x >= off) ? s[threadIdx.x - off] : 0;
        __syncthreads();
        s[threadIdx.x] += u;
        __syncthreads();
    }
    int prefix = block_offs[blockIdx.x] + ((threadIdx.x == 0) ? 0 : s[threadIdx.x - 1]);
#pragma unroll
    for (int j = 0; j < 4; ++j) {
        int idx = base + j;
        if (idx < NN) {
            row_ptr[idx] = prefix;
            cursor[idx]  = prefix;
            prefix += v[j];
        }
    }
}

// Scatter edges into row-sorted order (col_s, vv_s). Order within a row is
// nondeterministic — only changes fp32 summation order, within tolerance.
__global__ void scatter_kernel(const int* __restrict__ row, const int* __restrict__ col,
                               const float* __restrict__ vv, int* __restrict__ cursor,
                               int* __restrict__ col_s, float* __restrict__ vv_s, int E) {
    int e = blockIdx.x * blockDim.x + threadIdx.x;
    if (e >= E) return;
    int p = atomicAdd(&cursor[row[e]], 1);
    col_s[p] = col[e];
    vv_s[p]  = vv[e];
}

// ===================== main pipeline =====================

// xT[i*BT + bt] = logits[bt*NN + i]  (tiled LDS transpose)
__global__ void transpose_kernel(const float* __restrict__ logits, float* __restrict__ xT) {
    __shared__ float s[32][33];
    int tx = threadIdx.x & 31;
    int ty = threadIdx.x >> 5;
    int i0  = blockIdx.x * 32;
    int bt0 = blockIdx.y * 32;
    int i = i0 + tx;
#pragma unroll
    for (int r = 0; r < 4; ++r) {
        int bt = bt0 + ty + r * 8;
        if (i < NN) s[ty + r * 8][tx] = logits[(size_t)bt * NN + i];   // coalesced over i
    }
    __syncthreads();
#pragma unroll
    for (int r = 0; r < 4; ++r) {
        int i2 = i0 + ty + r * 8;
        if (i2 < NN) xT[(size_t)i2 * BT + bt0 + tx] = s[tx][ty + r * 8]; // coalesced over bt
    }
}

// One 64-lane wave per row: accT[i,:] = (sum_e vv*xT[col_e,:]) / (sum_e vv).
// No atomics; one contiguous 1 KB gather per edge, one 1 KB write per row.
__global__ void row_gather_kernel(const int* __restrict__ row_ptr,
                                  const int* __restrict__ col_s,
                                  const float* __restrict__ vv_s,
                                  const float* __restrict__ xT,
                                  float* __restrict__ accT) {
    int i = blockIdx.x * 4 + (threadIdx.x >> 6);
    if (i >= NN) return;
    int lane = threadIdx.x & 63;
    int k0 = row_ptr[i], k1 = row_ptr[i + 1];
    float4 acc = make_float4(0.f, 0.f, 0.f, 0.f);
    float rs = 0.f;
    for (int k = k0; k < k1; ++k) {
        int   c = col_s[k];      // wave-uniform broadcast load
        float v = vv_s[k];
        rs += v;
        float4 x = ((const float4*)(xT + (size_t)c * BT))[lane];
        acc.x += v * x.x; acc.y += v * x.y; acc.z += v * x.z; acc.w += v * x.w;
    }
    float inv = (rs > 0.f) ? (1.0f / rs) : 0.f;
    ((float4*)(accT + (size_t)i * BT))[lane] =
        make_float4(acc.x * inv, acc.y * inv, acc.z * inv, acc.w * inv);
}

// out[bt,i] = logits[bt,i] + accT[i,bt]  (tiled transpose; accT pre-normalized)
__global__ void finalize_kernel(const float* __restrict__ logits, const float* __restrict__ accT,
                                float* __restrict__ out) {
    __shared__ float s[32][33];
    int tx = threadIdx.x & 31;
    int ty = threadIdx.x >> 5;
    int i0  = blockIdx.x * 32;
    int bt0 = blockIdx.y * 32;
#pragma unroll
    for (int r = 0; r < 4; ++r) {
        int il = ty + r * 8;
        int i = i0 + il;
        if (i < NN) s[il][tx] = accT[(size_t)i * BT + bt0 + tx];   // coalesced over bt
    }
    __syncthreads();
#pragma unroll
    for (int r = 0; r < 4; ++r) {
        int bt = bt0 + ty + r * 8;
        int i = i0 + tx;
        if (i < NN) {
            size_t idx = (size_t)bt * NN + i;
            out[idx] = logits[idx] + s[tx][ty + r * 8];            // coalesced over i
        }
    }
}

// ===================== fallback (atomic) path kernels =====================

__global__ void rowsum_kernel(const int* __restrict__ row, const float* __restrict__ vv,
                              float* __restrict__ row_sum, int E) {
    int e = blockIdx.x * blockDim.x + threadIdx.x;
    if (e < E) atomicAdd(&row_sum[row[e]], vv[e]);
}

__global__ void edge_kernel(const int* __restrict__ row, const int* __restrict__ col,
                            const float* __restrict__ vv, const float* __restrict__ xT,
                            float* __restrict__ acc, int E) {
    int e = blockIdx.x * 4 + (threadIdx.x >> 6);
    if (e >= E) return;
    int lane = threadIdx.x & 63;
    int r = row[e];
    int c = col[e];
    float v = vv[e];
    float4 x4 = ((const float4*)(xT + (size_t)c * BT))[lane];
    float* dst = acc + (size_t)r * BT + lane * 4;
    atomicAdd(dst + 0, v * x4.x);
    atomicAdd(dst + 1, v * x4.y);
    atomicAdd(dst + 2, v * x4.z);
    atomicAdd(dst + 3, v * x4.w);
}

__global__ void finalize_div_kernel(const float* __restrict__ logits, const float* __restrict__ acc,
                                    const float* __restrict__ row_sum, float* __restrict__ out) {
    __shared__ float s[32][33];
    __shared__ float rs[32];
    int tx = threadIdx.x & 31;
    int ty = threadIdx.x >> 5;
    int i0  = blockIdx.x * 32;
    int bt0 = blockIdx.y * 32;
#pragma unroll
    for (int r = 0; r < 4; ++r) {
        int il = ty + r * 8;
        int i = i0 + il;
        if (i < NN) s[il][tx] = acc[(size_t)i * BT + bt0 + tx];
    }
    if (threadIdx.x < 32) {
        int i = i0 + (int)threadIdx.x;
        rs[threadIdx.x] = (i < NN) ? row_sum[i] : 1.0f;
    }
    __syncthreads();
#pragma unroll
    for (int r = 0; r < 4; ++r) {
        int bt = bt0 + ty + r * 8;
        int i = i0 + tx;
        if (i < NN) {
            size_t idx = (size_t)bt * NN + i;
            out[idx] = logits[idx] + s[tx][ty + r * 8] / rs[tx];
        }
    }
}

extern "C" void kernel_launch(void* const* d_in, const int* in_sizes, int n_in,
                              void* d_out, int out_size, void* d_ws, size_t ws_size,
                              hipStream_t stream) {
    const float* logits = (const float*)d_in[0];
    const float* vv     = (const float*)d_in[1];
    const int*   ei     = (const int*)d_in[2];
    const int E = in_sizes[1];
    const int* row = ei;        // edge_index[0]
    const int* col = ei + E;    // edge_index[1]
    float* out = (float*)d_out;

    const size_t accN = (size_t)NN * BT;   // 29,952,000 elems

    dim3 tgrid((NN + 31) / 32, BT / 32);
    const int e_blocks   = (E + 255) / 256;
    const int row_blocks = (NN + 3) / 4;

    // CSR-path workspace layout
    //   xT         : accN floats
    //   accT       : accN floats
    //   row_ptr    : NN+1 ints (doubles as count during histogram)
    //   cursor     : NN ints
    //   col_s      : E ints
    //   vv_s       : E floats
    //   block_sums : SCAN_NB ints
    const size_t need_csr = (2 * accN) * sizeof(float)
                          + (size_t)(NN + 1 + NN + E + SCAN_NB) * sizeof(int)
                          + (size_t)E * sizeof(float);

    if (ws_size >= need_csr) {
        float* xT         = (float*)d_ws;
        float* accT       = xT + accN;
        int*   row_ptr    = (int*)(accT + accN);
        int*   cursor     = row_ptr + (NN + 1);
        int*   col_s      = cursor + NN;
        float* vv_s       = (float*)(col_s + E);
        int*   block_sums = (int*)(vv_s + E);

        hipMemsetAsync(row_ptr, 0, (NN + 1) * sizeof(int), stream);
        hist_kernel<<<e_blocks, 256, 0, stream>>>(row, row_ptr, E);
        scan_phase1<<<SCAN_NB, 256, 0, stream>>>(row_ptr, block_sums);
        scan_phase2<<<1, SCAN_P2_T, 0, stream>>>(block_sums, row_ptr);
        scan_phase3<<<SCAN_NB, 256, 0, stream>>>(row_ptr, block_sums, cursor);
        scatter_kernel<<<e_blocks, 256, 0, stream>>>(row, col, vv, cursor, col_s, vv_s, E);
        transpose_kernel<<<tgrid, 256, 0, stream>>>(logits, xT);
        row_gather_kernel<<<row_blocks, 256, 0, stream>>>(row_ptr, col_s, vv_s, xT, accT);
        finalize_kernel<<<tgrid, 256, 0, stream>>>(logits, accT, out);
    } else {
        // Fallback: atomic-scatter path (known-passing).
        float* acc     = (float*)d_ws;
        float* xT      = acc + accN;
        float* row_sum = xT + accN;
        hipMemsetAsync(acc, 0, accN * sizeof(float), stream);
        hipMemsetAsync(row_sum, 0, NN * sizeof(float), stream);
        rowsum_kernel<<<e_blocks, 256, 0, stream>>>(row, vv, row_sum, E);
        transpose_kernel<<<tgrid, 256, 0, stream>>>(logits, xT);
        edge_kernel<<<(E + 3) / 4, 256, 0, stream>>>(row, col, vv, xT, acc, E);
        finalize_div_kernel<<<tgrid, 256, 0, stream>>>(logits, acc, row_sum, out);
    }
}